// Round 4
// baseline (215.369 us; speedup 1.0000x reference)
//
#include <hip/hip_runtime.h>
#include <hip/hip_bf16.h>

#define CIN  64
#define HH   128
#define WW   128
#define COUT 128
#define HO   126
#define WO   126
#define NB   32
#define HW   (HH * WW)

typedef __bf16 bf16x8 __attribute__((ext_vector_type(8)));
typedef float f32x4  __attribute__((ext_vector_type(4)));
typedef float f32x16 __attribute__((ext_vector_type(16)));

// reorder weight [128][64][3][3] f32 -> ws [9][128][64] bf16
__global__ void wreorder_3556(const float* __restrict__ w, unsigned short* __restrict__ ws) {
    int idx = blockIdx.x * 256 + threadIdx.x;
    if (idx >= 9 * 128 * 64) return;
    int s = idx >> 13;
    int r = idx & 8191;
    int cout = r >> 6, ci = r & 63;
    __bf16 h = (__bf16)w[cout * 576 + ci * 9 + s];
    ws[idx] = __builtin_bit_cast(unsigned short, h);
}

// LDS: xs[row(3)][col(130)][ci(64)] bf16, granule XOR-swizzled by col&7
// epilogue reuses xs bytes for the 32KB split-K exchange; pmin separate
#define XS_BYTES   (3 * 130 * 128)            // 49920
#define SMEM_BYTES (XS_BYTES + 4 * 128 * 4)   // 51968

template<bool USE_WS>
__global__ __launch_bounds__(1024, 4)
void conv_min_tanh_3556(const float* __restrict__ x, const float* __restrict__ w,
                        const float* __restrict__ bias,
                        const unsigned short* __restrict__ wsr,
                        float* __restrict__ out) {
    __shared__ __align__(16) unsigned char smem[SMEM_BYTES];
    unsigned char* xs = smem;
    float* pmin = (float*)(smem + XS_BYTES);

    // XCD-chunked bijective swizzle (4032 % 8 == 0)
    const int bid = blockIdx.x;
    const int blk = (bid & 7) * (NB * HO / 8) + (bid >> 3);
    const int b  = blk / HO;
    const int ho = blk - b * HO;

    const int tid  = threadIdx.x;
    const int lane = tid & 63;
    const int wid  = tid >> 6;          // 0..15
    const int waveM = wid & 3;          // cout base 32*waveM
    const int waveN = (wid >> 2) & 1;   // col base 64*waveN
    const int waveK = wid >> 3;         // ci half 32*waveK
    const int l31 = lane & 31;
    const int l5  = lane >> 5;
    const int mbase = waveM * 32;
    const int cb    = waveN * 64;

    // ---- stage x tile: 768 granules (4 cols x 8 ci each), f32x4 global loads
    {
        const float* xb = x + (size_t)b * (CIN * HW);
        if (tid < 768) {
            int g = tid;
            int col4 = g & 31;
            int cig  = (g >> 5) & 7;
            int row  = g >> 8;
            const float* src = xb + (size_t)(cig * 8) * HW + (size_t)(ho + row) * WW + col4 * 4;
            f32x4 v[8];
            #pragma unroll
            for (int j = 0; j < 8; ++j) v[j] = *(const f32x4*)(src + (size_t)j * HW);
            #pragma unroll
            for (int c = 0; c < 4; ++c) {
                bf16x8 gr;
                #pragma unroll
                for (int j = 0; j < 8; ++j) gr[j] = (__bf16)v[j][c];
                int col = col4 * 4 + c;
                int addr = (row * 130 + col) * 128 + ((cig ^ (col & 7)) << 4);
                *(bf16x8*)(xs + addr) = gr;
            }
        } else if (tid < 816) {
            // zero-pad cols 128,129 (touched by kw-shifted frags of discarded outputs)
            int t2 = tid - 768;                 // 0..47
            int row = t2 >> 4, col = 128 + ((t2 >> 3) & 1), cig = t2 & 7;
            bf16x8 z = {};
            int addr = (row * 130 + col) * 128 + ((cig ^ (col & 7)) << 4);
            *(bf16x8*)(xs + addr) = z;
        }
    }

    // ---- this wave's weights: 32 couts x K=32 -> af[9][2] = 72 VGPRs
    bf16x8 af[9][2];
    if (USE_WS) {
        const unsigned short* wbase = wsr + (size_t)(mbase + l31) * 64 + waveK * 32 + l5 * 8;
        #pragma unroll
        for (int s = 0; s < 9; ++s)
            #pragma unroll
            for (int t = 0; t < 2; ++t)
                af[s][t] = *(const bf16x8*)(wbase + s * 8192 + t * 16);
    } else {
        #pragma unroll
        for (int s = 0; s < 9; ++s)
            #pragma unroll
            for (int t = 0; t < 2; ++t)
                #pragma unroll
                for (int j = 0; j < 8; ++j)
                    af[s][t][j] = (__bf16)w[(mbase + l31) * 576 +
                                            (waveK * 32 + t * 16 + l5 * 8 + j) * 9 + s];
    }

    __syncthreads();   // xs ready; barrier drain also makes af resident

    // ---- precomputed swizzled B addresses: addr = kh*16640 + (PA[nt][kw] ^ (t<<5))
    // granule g = waveK*4 + t*2 + l5 (disjoint bits -> XOR == add)
    int PA[2][3];
    #pragma unroll
    for (int nt = 0; nt < 2; ++nt)
        #pragma unroll
        for (int kw = 0; kw < 3; ++kw) {
            int col = cb + nt * 32 + l31 + kw;
            PA[nt][kw] = col * 128 + (((waveK * 4 + l5) ^ (col & 7)) << 4);
        }

    f32x16 acc[2] = {};

    // ---- barrier-free K-loop: 9 slices x 2 ksteps x 2 ntiles
    #pragma unroll
    for (int s = 0; s < 9; ++s) {
        const int kh = s / 3, kw = s - kh * 3;       // compile-time
        const int khoff = kh * 16640;
        #pragma unroll
        for (int t = 0; t < 2; ++t) {
            bf16x8 b0 = *(const bf16x8*)(xs + khoff + (PA[0][kw] ^ (t << 5)));
            bf16x8 b1 = *(const bf16x8*)(xs + khoff + (PA[1][kw] ^ (t << 5)));
            acc[0] = __builtin_amdgcn_mfma_f32_32x32x16_bf16(af[s][t], b0, acc[0], 0, 0, 0);
            acc[1] = __builtin_amdgcn_mfma_f32_32x32x16_bf16(af[s][t], b1, acc[1], 0, 0, 0);
        }
    }

    __syncthreads();   // all LDS reads of xs done; safe to reuse for exchange

    // ---- split-K combine: two 32KB stages through LDS, conflict-free [chunk][lane]
    const int p = waveM * 2 + waveN;                // 0..7
    unsigned char* ex = smem + p * 4096;            // 8 pairs x 4KB
    float pm[2];

    #pragma unroll
    for (int nt = 0; nt < 2; ++nt) {
        if (nt) __syncthreads();                    // prev stage reads done
        if (waveK == 1) {
            #pragma unroll
            for (int c = 0; c < 4; ++c) {
                f32x4 ch = { acc[nt][c*4+0], acc[nt][c*4+1], acc[nt][c*4+2], acc[nt][c*4+3] };
                *(f32x4*)(ex + c * 1024 + lane * 16) = ch;
            }
        }
        __syncthreads();
        if (waveK == 0) {
            float m = 1e30f;
            const int rbase = mbase + 4 * l5;
            #pragma unroll
            for (int c = 0; c < 4; ++c) {
                f32x4 o = *(const f32x4*)(ex + c * 1024 + lane * 16);
                #pragma unroll
                for (int q = 0; q < 4; ++q) {
                    int r = c * 4 + q;
                    float bv = bias[rbase + (r & 3) + 8 * (r >> 2)];
                    m = fminf(m, acc[nt][r] + o[q] + bv);
                }
            }
            pm[nt] = m;
        }
    }

    if (waveK == 0) {
        pm[0] = fminf(pm[0], __shfl_xor(pm[0], 32, 64));
        pm[1] = fminf(pm[1], __shfl_xor(pm[1], 32, 64));
        if (l5 == 0) {
            pmin[waveM * 128 + cb + l31]      = pm[0];
            pmin[waveM * 128 + cb + 32 + l31] = pm[1];
        }
    }
    __syncthreads();
    if (tid < WO) {
        float v = fminf(fminf(pmin[tid], pmin[128 + tid]),
                        fminf(pmin[256 + tid], pmin[384 + tid]));
        v = tanhf(tanhf(v));
        out[((size_t)b * HO + ho) * WO + tid] = v;
    }
}

extern "C" void kernel_launch(void* const* d_in, const int* in_sizes, int n_in,
                              void* d_out, int out_size, void* d_ws, size_t ws_size,
                              hipStream_t stream) {
    const float* x    = (const float*)d_in[0];
    const float* w    = (const float*)d_in[1];
    const float* bias = (const float*)d_in[2];
    float* out = (float*)d_out;

    const size_t ws_needed = (size_t)9 * 128 * 64 * 2;   // 147456 B
    if (ws_size >= ws_needed) {
        unsigned short* wsb = (unsigned short*)d_ws;
        wreorder_3556<<<288, 256, 0, stream>>>(w, wsb);
        conv_min_tanh_3556<true><<<NB * HO, 1024, 0, stream>>>(x, w, bias, wsb, out);
    } else {
        conv_min_tanh_3556<false><<<NB * HO, 1024, 0, stream>>>(x, w, bias, nullptr, out);
    }
}

// Round 6
// 89.875 us; speedup vs baseline: 2.3963x; 2.3963x over previous
//
#include <hip/hip_runtime.h>
#include <hip/hip_bf16.h>

#define CIN  64
#define HH   128
#define WW   128
#define COUT 128
#define HO   126
#define WO   126
#define NB   32
#define HW   (HH * WW)

typedef __bf16 bf16x8 __attribute__((ext_vector_type(8)));
typedef float f32x16 __attribute__((ext_vector_type(16)));

// ws2 granule layout: [step(18)=(s,h)][kg(4)][cout(128)] 16B granules
// granule(s,h,kg,cout)[j] = bf16(w[cout][ci = 32h + 8kg + j][s])
__global__ void wreorder_3556(const float* __restrict__ w, unsigned short* __restrict__ ws2) {
    int e = blockIdx.x * 256 + threadIdx.x;      // 0..73727
    if (e >= 73728) return;
    int j = e & 7, cout = (e >> 3) & 127, kg = (e >> 10) & 3, h = (e >> 12) & 1, s = e >> 13;
    __bf16 v = (__bf16)w[cout * 576 + (h * 32 + kg * 8 + j) * 9 + s];
    ws2[e] = __builtin_bit_cast(unsigned short, v);
}

// LDS: xs [row(3)][cg(8)][col(130)] 16B granules (ci-major) @0 | pmin[2][128] @49920
#define XS_OFF  0
#define PM_OFF  49920
#define SMEM_BYTES (49920 + 2 * 128 * 4)   // 50944 -> 3 blocks/CU

template<bool USE_WS>
__global__ __launch_bounds__(256, 3)
void conv_min_tanh_3556(const float* __restrict__ x, const float* __restrict__ w,
                        const float* __restrict__ bias,
                        const unsigned char* __restrict__ wsr_b,
                        float* __restrict__ out) {
    __shared__ __align__(16) unsigned char smem[SMEM_BYTES];
    float* pmin = (float*)(smem + PM_OFF);

    // XCD-chunked bijective swizzle (4032 % 8 == 0)
    const int bid = blockIdx.x;
    const int blk = (bid & 7) * (NB * HO / 8) + (bid >> 3);
    const int b  = blk / HO;
    const int ho = blk - b * HO;

    const int tid  = threadIdx.x;
    const int lane = tid & 63;
    const int wid  = tid >> 6;
    const int l31 = lane & 31;
    const int l5  = lane >> 5;
    const int mb  = (wid >> 1) * 64;     // cout base (0 or 64)
    const int cb  = (wid & 1) * 64;      // col base  (0 or 64)

    // ---- stage x into xs[row][cg][col] granules; conflict-free 16B-stride writes
    // thread (cg = tid>>5, c0 = tid&31) covers cols {c0, c0+32, c0+64, c0+96}, rows 0..2
    {
        const int cg = tid >> 5, c0 = tid & 31;
        const float* xb = x + (size_t)b * CIN * HW + (size_t)(cg * 8) * HW + (size_t)ho * WW + c0;
        #pragma unroll
        for (int row = 0; row < 3; ++row) {
            #pragma unroll
            for (int i = 0; i < 4; ++i) {
                union { unsigned short us[8]; int4 i4; } p;
                #pragma unroll
                for (int j = 0; j < 8; ++j) {
                    __bf16 t = (__bf16)xb[(size_t)j * HW + (size_t)row * WW + i * 32];
                    p.us[j] = __builtin_bit_cast(unsigned short, t);
                }
                *(int4*)(smem + XS_OFF + ((row * 8 + cg) * 130 + i * 32 + c0) * 16) = p.i4;
            }
        }
        if (tid < 48) {   // zero-pad cols 128,129
            int row = tid >> 4, cgz = (tid >> 1) & 7, colz = 128 + (tid & 1);
            int4 z = {0, 0, 0, 0};
            *(int4*)(smem + XS_OFF + ((row * 8 + cgz) * 130 + colz) * 16) = z;
        }
    }
    __syncthreads();

    // ---- B read bases (stride-16B across lanes: conflict-free)
    // full addr = (kh*8 + h*4)*2080 + ks*4160 + baseB[n][kw]
    int baseB[2][3];
    #pragma unroll
    for (int n = 0; n < 2; ++n)
        #pragma unroll
        for (int kw = 0; kw < 3; ++kw)
            baseB[n][kw] = XS_OFF + (cb + n * 32 + l31 + kw) * 16 + l5 * 2080;

    // ---- A stream base: granule(step, kg=2ks+l5, cout=mb+m*32+l31)
    const unsigned char* wA = USE_WS ? (wsr_b + l5 * 2048 + (size_t)(mb + l31) * 16) : nullptr;

    auto LOAD_A = [&](int step, int ks, int m) -> bf16x8 {
        if constexpr (USE_WS) {
            return *(const bf16x8*)(wA + (size_t)step * 8192 + ks * 4096 + m * 512);
        } else {
            int s = step >> 1, h = step & 1;
            bf16x8 r;
            #pragma unroll
            for (int j = 0; j < 8; ++j)
                r[j] = (__bf16)w[(mb + m * 32 + l31) * 576 +
                                 (h * 32 + (2 * ks + l5) * 8 + j) * 9 + s];
            return r;
        }
    };

    // ---- 3-slot register pipeline for A
    bf16x8 A3[3][2][2];
    #pragma unroll
    for (int p = 0; p < 3; ++p)
        #pragma unroll
        for (int ks = 0; ks < 2; ++ks)
            #pragma unroll
            for (int m = 0; m < 2; ++m)
                A3[p][ks][m] = LOAD_A(p, ks, m);

    f32x16 acc[2][2] = {};

    #pragma unroll
    for (int step = 0; step < 18; ++step) {
        const int s = step >> 1, h = step & 1;
        const int kh = s / 3, kw = s % 3;           // compile-time after unroll
        const int rowOff = (kh * 8 + h * 4) * 2080;
        const int sl = step % 3;

        bf16x8 B[2][2];
        #pragma unroll
        for (int ks = 0; ks < 2; ++ks) {
            B[ks][0] = *(const bf16x8*)(smem + rowOff + ks * 4160 + baseB[0][kw]);
            B[ks][1] = *(const bf16x8*)(smem + rowOff + ks * 4160 + baseB[1][kw]);
        }
        #pragma unroll
        for (int ks = 0; ks < 2; ++ks)
            #pragma unroll
            for (int m = 0; m < 2; ++m)
                #pragma unroll
                for (int n = 0; n < 2; ++n)
                    acc[m][n] = __builtin_amdgcn_mfma_f32_32x32x16_bf16(
                        A3[sl][ks][m], B[ks][n], acc[m][n], 0, 0, 0);

        if (step + 3 < 18) {
            #pragma unroll
            for (int ks = 0; ks < 2; ++ks)
                #pragma unroll
                for (int m = 0; m < 2; ++m)
                    A3[sl][ks][m] = LOAD_A(step + 3, ks, m);
        }
    }

    // ---- epilogue: +bias, min over couts, cross-lane, cross-wave, tanh(tanh)
    float pm[2] = {1e30f, 1e30f};
    #pragma unroll
    for (int m = 0; m < 2; ++m) {
        #pragma unroll
        for (int r = 0; r < 16; ++r) {
            int row = mb + m * 32 + (r & 3) + 8 * (r >> 2) + 4 * l5;
            float bv = bias[row];
            pm[0] = fminf(pm[0], acc[m][0][r] + bv);
            pm[1] = fminf(pm[1], acc[m][1][r] + bv);
        }
    }
    pm[0] = fminf(pm[0], __shfl_xor(pm[0], 32, 64));
    pm[1] = fminf(pm[1], __shfl_xor(pm[1], 32, 64));
    if (l5 == 0) {
        pmin[(wid >> 1) * 128 + cb + l31]      = pm[0];
        pmin[(wid >> 1) * 128 + cb + 32 + l31] = pm[1];
    }
    __syncthreads();
    if (tid < WO) {
        float v = fminf(pmin[tid], pmin[128 + tid]);
        v = tanhf(tanhf(v));
        out[((size_t)b * HO + ho) * WO + tid] = v;
    }
}

extern "C" void kernel_launch(void* const* d_in, const int* in_sizes, int n_in,
                              void* d_out, int out_size, void* d_ws, size_t ws_size,
                              hipStream_t stream) {
    const float* x    = (const float*)d_in[0];
    const float* w    = (const float*)d_in[1];
    const float* bias = (const float*)d_in[2];
    float* out = (float*)d_out;

    const size_t ws_needed = (size_t)18 * 4 * 128 * 16;   // 147456 B
    if (ws_size >= ws_needed) {
        unsigned short* wsb = (unsigned short*)d_ws;
        wreorder_3556<<<288, 256, 0, stream>>>(w, wsb);
        conv_min_tanh_3556<true><<<NB * HO, 256, 0, stream>>>(x, w, bias, (const unsigned char*)wsb, out);
    } else {
        conv_min_tanh_3556<false><<<NB * HO, 256, 0, stream>>>(x, w, bias, nullptr, out);
    }
}

// Round 7
// 89.726 us; speedup vs baseline: 2.4003x; 1.0017x over previous
//
#include <hip/hip_runtime.h>
#include <hip/hip_bf16.h>

#define CIN  64
#define HH   128
#define WW   128
#define COUT 128
#define HO   126
#define WO   126
#define NB   32
#define HW   (HH * WW)

typedef __bf16 bf16x8 __attribute__((ext_vector_type(8)));
typedef float f32x16 __attribute__((ext_vector_type(16)));

// ws2 granule layout: [step(18)=(s,h)][kg(4)][cout(128)] 16B granules
// granule(s,h,kg,cout)[j] = bf16(w[cout][ci = 32h + 8kg + j][s])
__global__ void wreorder_3556(const float* __restrict__ w, unsigned short* __restrict__ ws2) {
    int e = blockIdx.x * 256 + threadIdx.x;      // 0..73727
    if (e >= 73728) return;
    int j = e & 7, cout = (e >> 3) & 127, kg = (e >> 10) & 3, h = (e >> 12) & 1, s = e >> 13;
    __bf16 v = (__bf16)w[cout * 576 + (h * 32 + kg * 8 + j) * 9 + s];
    ws2[e] = __builtin_bit_cast(unsigned short, v);
}

// LDS: xs [row(3)][cg(8)][col(130)] 16B granules (ci-major) @0 | pmin[2][128] @49920
#define XS_OFF  0
#define PM_OFF  49920
#define SMEM_BYTES (49920 + 2 * 128 * 4)   // 50944 -> 3 blocks/CU

template<bool USE_WS>
__global__ __launch_bounds__(256, 3)
void conv_min_tanh_3556(const float* __restrict__ x, const float* __restrict__ w,
                        const float* __restrict__ bias,
                        const unsigned char* __restrict__ wsr_b,
                        float* __restrict__ out) {
    __shared__ __align__(16) unsigned char smem[SMEM_BYTES];
    float* pmin = (float*)(smem + PM_OFF);

    // XCD-chunked bijective swizzle (4032 % 8 == 0)
    const int bid = blockIdx.x;
    const int blk = (bid & 7) * (NB * HO / 8) + (bid >> 3);
    const int b  = blk / HO;
    const int ho = blk - b * HO;

    const int tid  = threadIdx.x;
    const int lane = tid & 63;
    const int wid  = tid >> 6;
    const int l31 = lane & 31;
    const int l5  = lane >> 5;
    const int mb  = (wid >> 1) * 64;     // cout base (0 or 64)
    const int cb  = (wid & 1) * 64;      // col base  (0 or 64)

    // ---- stage x into xs[row][cg][col] granules; conflict-free 16B-stride writes
    {
        const int cg = tid >> 5, c0 = tid & 31;
        const float* xb = x + (size_t)b * CIN * HW + (size_t)(cg * 8) * HW + (size_t)ho * WW + c0;
        #pragma unroll
        for (int row = 0; row < 3; ++row) {
            #pragma unroll
            for (int i = 0; i < 4; ++i) {
                union { unsigned short us[8]; int4 i4; } p;
                #pragma unroll
                for (int j = 0; j < 8; ++j) {
                    __bf16 t = (__bf16)xb[(size_t)j * HW + (size_t)row * WW + i * 32];
                    p.us[j] = __builtin_bit_cast(unsigned short, t);
                }
                *(int4*)(smem + XS_OFF + ((row * 8 + cg) * 130 + i * 32 + c0) * 16) = p.i4;
            }
        }
        if (tid < 48) {   // zero-pad cols 128,129
            int row = tid >> 4, cgz = (tid >> 1) & 7, colz = 128 + (tid & 1);
            int4 z = {0, 0, 0, 0};
            *(int4*)(smem + XS_OFF + ((row * 8 + cgz) * 130 + colz) * 16) = z;
        }
    }
    __syncthreads();

    // ---- B read bases (stride-16B across lanes: conflict-free)
    // full addr = (kh*8 + h*4)*2080 + ks*4160 + baseB[n][kw]
    int baseB[2][3];
    #pragma unroll
    for (int n = 0; n < 2; ++n)
        #pragma unroll
        for (int kw = 0; kw < 3; ++kw)
            baseB[n][kw] = XS_OFF + (cb + n * 32 + l31 + kw) * 16 + l5 * 2080;

    // ---- A stream base: granule(step, kg=2ks+l5, cout=mb+m*32+l31)
    const unsigned char* wA = USE_WS ? (wsr_b + l5 * 2048 + (size_t)(mb + l31) * 16) : nullptr;

    auto LOAD_A = [&](int step, int ks, int m) -> bf16x8 {
        if constexpr (USE_WS) {
            return *(const bf16x8*)(wA + (size_t)step * 8192 + ks * 4096 + m * 512);
        } else {
            int s = step >> 1, h = step & 1;
            bf16x8 r;
            #pragma unroll
            for (int j = 0; j < 8; ++j)
                r[j] = (__bf16)w[(mb + m * 32 + l31) * 576 +
                                 (h * 32 + (2 * ks + l5) * 8 + j) * 9 + s];
            return r;
        }
    };

    // ---- 3-slot register pipeline for A (global->reg, issue 2 steps before use)
    bf16x8 A3[3][2][2];
    #pragma unroll
    for (int p = 0; p < 3; ++p)
        #pragma unroll
        for (int ks = 0; ks < 2; ++ks)
            #pragma unroll
            for (int m = 0; m < 2; ++m)
                A3[p][ks][m] = LOAD_A(p, ks, m);

    // ---- 2-slot register double-buffer for B (LDS->reg, issue 1 step before use)
    bf16x8 Bb[2][2][2];   // [buf][ks][n]
    #pragma unroll
    for (int ks = 0; ks < 2; ++ks) {
        Bb[0][ks][0] = *(const bf16x8*)(smem + ks * 4160 + baseB[0][0]);   // step0: kh=0,h=0,kw=0
        Bb[0][ks][1] = *(const bf16x8*)(smem + ks * 4160 + baseB[1][0]);
    }

    f32x16 acc[2][2] = {};

    #pragma unroll
    for (int step = 0; step < 18; ++step) {
        const int cur = step & 1, nxt = cur ^ 1;
        const int sl  = step % 3;

        // prefetch B for step+1 BEFORE consuming B(step)
        if (step + 1 < 18) {
            const int s1 = (step + 1) >> 1, h1 = (step + 1) & 1;
            const int kh1 = s1 / 3, kw1 = s1 % 3;               // compile-time
            const int ro1 = (kh1 * 8 + h1 * 4) * 2080;
            #pragma unroll
            for (int ks = 0; ks < 2; ++ks) {
                Bb[nxt][ks][0] = *(const bf16x8*)(smem + ro1 + ks * 4160 + baseB[0][kw1]);
                Bb[nxt][ks][1] = *(const bf16x8*)(smem + ro1 + ks * 4160 + baseB[1][kw1]);
            }
        }

        #pragma unroll
        for (int ks = 0; ks < 2; ++ks)
            #pragma unroll
            for (int m = 0; m < 2; ++m)
                #pragma unroll
                for (int n = 0; n < 2; ++n)
                    acc[m][n] = __builtin_amdgcn_mfma_f32_32x32x16_bf16(
                        A3[sl][ks][m], Bb[cur][ks][n], acc[m][n], 0, 0, 0);

        // reload A slot just consumed with step+3
        if (step + 3 < 18) {
            #pragma unroll
            for (int ks = 0; ks < 2; ++ks)
                #pragma unroll
                for (int m = 0; m < 2; ++m)
                    A3[sl][ks][m] = LOAD_A(step + 3, ks, m);
        }
    }

    // ---- epilogue: +bias, min over couts, cross-lane, cross-wave, tanh(tanh)
    float pm[2] = {1e30f, 1e30f};
    #pragma unroll
    for (int m = 0; m < 2; ++m) {
        #pragma unroll
        for (int r = 0; r < 16; ++r) {
            int row = mb + m * 32 + (r & 3) + 8 * (r >> 2) + 4 * l5;
            float bv = bias[row];
            pm[0] = fminf(pm[0], acc[m][0][r] + bv);
            pm[1] = fminf(pm[1], acc[m][1][r] + bv);
        }
    }
    pm[0] = fminf(pm[0], __shfl_xor(pm[0], 32, 64));
    pm[1] = fminf(pm[1], __shfl_xor(pm[1], 32, 64));
    if (l5 == 0) {
        pmin[(wid >> 1) * 128 + cb + l31]      = pm[0];
        pmin[(wid >> 1) * 128 + cb + 32 + l31] = pm[1];
    }
    __syncthreads();
    if (tid < WO) {
        float v = fminf(pmin[tid], pmin[128 + tid]);
        v = tanhf(tanhf(v));
        out[((size_t)b * HO + ho) * WO + tid] = v;
    }
}

extern "C" void kernel_launch(void* const* d_in, const int* in_sizes, int n_in,
                              void* d_out, int out_size, void* d_ws, size_t ws_size,
                              hipStream_t stream) {
    const float* x    = (const float*)d_in[0];
    const float* w    = (const float*)d_in[1];
    const float* bias = (const float*)d_in[2];
    float* out = (float*)d_out;

    const size_t ws_needed = (size_t)18 * 4 * 128 * 16;   // 147456 B
    if (ws_size >= ws_needed) {
        unsigned short* wsb = (unsigned short*)d_ws;
        wreorder_3556<<<288, 256, 0, stream>>>(w, wsb);
        conv_min_tanh_3556<true><<<NB * HO, 256, 0, stream>>>(x, w, bias, (const unsigned char*)wsb, out);
    } else {
        conv_min_tanh_3556<false><<<NB * HO, 256, 0, stream>>>(x, w, bias, nullptr, out);
    }
}